// Round 7
// baseline (317.536 us; speedup 1.0000x reference)
//
#include <hip/hip_runtime.h>
#include <stdint.h>

#define BATCH 8
#define MPTS 500000
#define NPTS (BATCH * MPTS)      // 4,000,000
#define GRIDV 2097152            // 128^3 voxels per batch
#define NBQ 1024                 // 8 batches * (4*4*8) sub-blocks of 32x32x16
#define GPB 977                  // point-groups (of 4) per scatter block: ceil(125000/128)

template <int NT>
__device__ __forceinline__ void block_reduce2(float& tv, float& mse) {
    for (int off = 32; off > 0; off >>= 1) {
        tv  += __shfl_down(tv, off, 64);
        mse += __shfl_down(mse, off, 64);
    }
    __shared__ float stv[NT / 64], sms[NT / 64];
    int w = threadIdx.x >> 6, lane = threadIdx.x & 63;
    if (lane == 0) { stv[w] = tv; sms[w] = mse; }
    __syncthreads();
    if (threadIdx.x == 0) {
        float a = 0.f, m = 0.f;
        #pragma unroll
        for (int e = 0; e < NT / 64; ++e) { a += stv[e]; m += sms[e]; }
        tv = a; mse = m;
    }
}

// K1: direct scatter-add into global per-batch 128^3 grid. Returnless f32
// atomics (fire-and-forget, no dependent use). batch = blockIdx&7 so under
// round-robin block->XCD dispatch each XCD's atomics target one batch's 8 MB
// grid slice (mostly L2-local; correctness doesn't depend on the mapping).
// Point loads identical to the proven sort_k phase-1 pattern (3 int4 + float4
// per 4-point group; groups never straddle a batch since MPTS%4==0).
__global__ void __launch_bounds__(1024) scat_k(const int* __restrict__ idx,
                                               const float* __restrict__ val,
                                               float* __restrict__ grid) {
    int b = blockIdx.x & 7;
    int chunk = blockIdx.x >> 3;          // 0..127 within batch
    int g = chunk * GPB + threadIdx.x;    // 4-point group within batch
    if (threadIdx.x >= GPB || g >= (MPTS / 4)) return;
    size_t p = (size_t)b * MPTS + (size_t)g * 4;
    const int4* ip = (const int4*)(idx + p * 3);
    int4 A = ip[0], B = ip[1], C = ip[2];
    float4 V = *(const float4*)(val + p);
    float* gb = grid + (size_t)b * GRIDV;
    atomicAdd(&gb[A.x * 16384 + A.y * 128 + A.z], V.x);
    atomicAdd(&gb[A.w * 16384 + B.x * 128 + B.y], V.y);
    atomicAdd(&gb[B.z * 16384 + B.w * 128 + C.x], V.z);
    atomicAdd(&gb[C.y * 16384 + C.z * 128 + C.w], V.w);
}

// K2: stencil with natural halo from the global grid — no faces machinery.
// Block -> sub-block qb (32x32x16); thread t owns line (il = t>>5, jl = t&31),
// 16 k-voxels. Each adjacent-pair diff is counted exactly once by its lower
// element's owner; pairs crossing the sub-block boundary read the neighbor
// sub-block's plane directly (global layout makes the halo free). Same
// batch-per-XCD swizzle as scat_k so reads hit the XCD-local L2/L3 slice.
__global__ void __launch_bounds__(1024) sten_k(const float* __restrict__ grid,
                                               float2* __restrict__ pa) {
    int qb = ((blockIdx.x & 7) << 7) | (blockIdx.x >> 3);   // bijective
    int b = qb >> 7, bi = (qb >> 5) & 3, bj = (qb >> 3) & 3, bk = qb & 7;
    int il = threadIdx.x >> 5, jl = threadIdx.x & 31;
    int i = bi * 32 + il, j = bj * 32 + jl, k0 = bk * 16;
    const float* own = grid + (size_t)b * GRIDV + i * 16384 + j * 128 + k0;
    float v[16];
    #pragma unroll
    for (int c = 0; c < 4; ++c)
        *(float4*)&v[c * 4] = *(const float4*)(own + c * 4);
    float tv = 0.f, mse = 0.f;
    // k-axis: 15 interior pairs + halo pair (k0+15, k0+16) if bk < 7
    #pragma unroll
    for (int k = 0; k < 15; ++k) {
        float d = v[k + 1] - v[k]; tv += fabsf(d); mse += d * d;
    }
    if (bk < 7) {
        float d = own[16] - v[15]; tv += fabsf(d); mse += d * d;
    }
    // j-axis: pair (j, j+1) for all 16 k, if j < 127
    if (j < 127) {
        const float* jn = own + 128;
        #pragma unroll
        for (int c = 0; c < 4; ++c) {
            float4 w = *(const float4*)(jn + c * 4);
            float d0 = w.x - v[c*4+0], d1 = w.y - v[c*4+1];
            float d2 = w.z - v[c*4+2], d3 = w.w - v[c*4+3];
            tv  += fabsf(d0) + fabsf(d1) + fabsf(d2) + fabsf(d3);
            mse += d0*d0 + d1*d1 + d2*d2 + d3*d3;
        }
    }
    // i-axis: pair (i, i+1) for all 16 k, if i < 127
    if (i < 127) {
        const float* in_ = own + 16384;
        #pragma unroll
        for (int c = 0; c < 4; ++c) {
            float4 w = *(const float4*)(in_ + c * 4);
            float d0 = w.x - v[c*4+0], d1 = w.y - v[c*4+1];
            float d2 = w.z - v[c*4+2], d3 = w.w - v[c*4+3];
            tv  += fabsf(d0) + fabsf(d1) + fabsf(d2) + fabsf(d3);
            mse += d0*d0 + d1*d1 + d2*d2 + d3*d3;
        }
    }
    block_reduce2<1024>(tv, mse);
    if (threadIdx.x == 0) pa[qb] = make_float2(tv, mse);
}

// K3: final reduction — one block per batch over 128 sub-block partials
__global__ void __launch_bounds__(256) final_k(const float2* __restrict__ pa,
                                               float* __restrict__ out) {
    int b = blockIdx.x;
    float tv = 0.f, mse = 0.f;
    for (int q = threadIdx.x; q < NBQ / BATCH; q += 256) {
        float2 v = pa[b * (NBQ / BATCH) + q]; tv += v.x; mse += v.y;
    }
    block_reduce2<256>(tv, mse);
    if (threadIdx.x == 0) {
        out[b]     = tv  * (1.f / 2097152.f);   // / X^3
        out[8 + b] = mse * (1.f / 32512.f);     // / (2X^2-2X)
    }
}

extern "C" void kernel_launch(void* const* d_in, const int* in_sizes, int n_in,
                              void* d_out, int out_size, void* d_ws, size_t ws_size,
                              hipStream_t stream) {
    const int*   indices = (const int*)d_in[0];   // (B, M, 3) int32
    const float* values  = (const float*)d_in[1]; // (B, M) float32
    float*       out     = (float*)d_out;         // (2, B) float32

    // workspace: grid 64 MB + pa 8 KB (256B-aligned sections)
    char* wp = (char*)d_ws;
    float* gridbuf = (float*)wp;                              // B*128^3 f32 (64 MB)
    wp += (((size_t)BATCH * GRIDV * 4) + 255) & ~(size_t)255;
    float2* pa = (float2*)wp;                                 // NBQ (8 KB)

    hipMemsetAsync(gridbuf, 0, (size_t)BATCH * GRIDV * 4, stream);
    scat_k <<<NBQ,   1024, 0, stream>>>(indices, values, gridbuf);
    sten_k <<<NBQ,   1024, 0, stream>>>(gridbuf, pa);
    final_k<<<BATCH, 256,  0, stream>>>(pa, out);
}

// Round 8
// 154.079 us; speedup vs baseline: 2.0609x; 2.0609x over previous
//
#include <hip/hip_runtime.h>
#include <stdint.h>

#define BATCH 8
#define MPTS 500000
#define NPTS (BATCH * MPTS)            // 4,000,000
#define NBQ 1024                       // 8 batches * (4*4*8) sub-blocks of 32x32x16
#define TP 8192                        // points per tile (srt = 32 KB)
#define NTILE ((NPTS + TP - 1) / TP)   // 489
#define RSLOT 5376                     // rec slots per bucket (mean use ~4640, +11 sd)
#define CSTR 16                        // gcur stride in dwords (64 B -> own cache line)
#define NIFACE 304                     // interfaces per batch: 96 + 96 + 112
#define NBND (BATCH * NIFACE)          // 2432 boundary blocks

template <int NT>
__device__ __forceinline__ void block_reduce2(float& tv, float& mse) {
    for (int off = 32; off > 0; off >>= 1) {
        tv  += __shfl_down(tv, off, 64);
        mse += __shfl_down(mse, off, 64);
    }
    __shared__ float stv[NT / 64], sms[NT / 64];
    int w = threadIdx.x >> 6, lane = threadIdx.x & 63;
    if (lane == 0) { stv[w] = tv; sms[w] = mse; }
    __syncthreads();
    if (threadIdx.x == 0) {
        float a = 0.f, m = 0.f;
        #pragma unroll
        for (int e = 0; e < NT / 64; ++e) { a += stv[e]; m += sms[e]; }
        tv = a; mse = m;
    }
}

// aux = (q:10 | l:14); sub-block 32x32x16. aux < 2^24 -> 0xFFFFFFFF safe sentinel.
__device__ __forceinline__ uint32_t pack_aux(int b, int i, int j, int k) {
    uint32_t q = ((uint32_t)b << 7) | ((uint32_t)(i >> 5) << 5) |
                 ((uint32_t)(j >> 5) << 3) | (uint32_t)(k >> 4);
    uint32_t l = ((uint32_t)(i & 31) << 9) | ((uint32_t)(j & 31) << 4) | (uint32_t)(k & 15);
    return (q << 14) | l;
}

// LDS bank swizzle: line s = il*32+jl holds 16 dwords; group-of-4 index XORed
// with (s>>1) so wave-wide b128 reads spread across all 32 banks.
__device__ __forceinline__ int gaddr(int s, int kl) {
    return s * 16 + (kl & 3) + ((((kl >> 2) ^ (s >> 1)) & 3) << 2);
}
__device__ __forceinline__ int goff(int s, int c) {
    return ((c ^ (s >> 1)) & 3) << 2;
}

// round float bits to top-16 (sign+exp+7man), round-half-up
__device__ __forceinline__ uint32_t val16(float f) {
    return (__float_as_uint(f) + 0x8000u) >> 16;
}
__device__ __forceinline__ float f16up(uint16_t u) {
    return __uint_as_float(((uint32_t)u) << 16);
}

// K1: per-tile hist + local scan + LDS counting sort, then BUCKET-CONTIGUOUS
// global writeout. Thread q = bucket q: reserves cq4 = ceil4(cq) slots in
// bucket q's region via one returnful global atomic (64B-strided cursors ->
// no line contention; issued 2 barriers before use -> latency hidden), then
// writes its run as aligned dwordx4, tail-padded with record 0u (decodes to
// +0.0f into voxel 0 -> numerically inert). Removes hoff entirely.
__global__ void __launch_bounds__(1024, 8) sort_k(const int* __restrict__ idx,
                                                  const float* __restrict__ val,
                                                  uint32_t* __restrict__ gcur,
                                                  uint32_t* __restrict__ rec) {
    __shared__ uint32_t h[NBQ];     // counts -> placement cursors
    __shared__ uint32_t wtot[16];
    __shared__ uint32_t srt[TP];    // bucket-sorted packed records (32 KB)
    int tile = blockIdx.x;
    int p0 = tile * TP;
    int cnt = min(TP, NPTS - p0);   // always a multiple of 4
    h[threadIdx.x] = 0;
    __syncthreads();
    // phase 1: vectorized loads (4 points = 3 int4 + 1 float4), LDS histogram.
    uint32_t a[8]; uint32_t vpk[4];
    int ng = cnt >> 2;
    #pragma unroll
    for (int e = 0; e < 2; ++e) {
        int g = threadIdx.x + e * 1024;
        if (g < ng) {
            int p = p0 + g * 4;
            const int4* ip = (const int4*)(idx + (size_t)p * 3);
            int4 A = ip[0], B = ip[1], C = ip[2];
            float4 V = *(const float4*)(val + p);
            int b = p / MPTS;       // groups of 4 never straddle a batch
            a[4*e+0] = pack_aux(b, A.x, A.y, A.z);
            a[4*e+1] = pack_aux(b, A.w, B.x, B.y);
            a[4*e+2] = pack_aux(b, B.z, B.w, C.x);
            a[4*e+3] = pack_aux(b, C.y, C.z, C.w);
            vpk[2*e]     = val16(V.x) | (val16(V.y) << 16);
            vpk[2*e + 1] = val16(V.z) | (val16(V.w) << 16);
            #pragma unroll
            for (int u = 0; u < 4; ++u) atomicAdd(&h[a[4*e+u] >> 14], 1u);
        } else {
            a[4*e+0] = a[4*e+1] = a[4*e+2] = a[4*e+3] = 0xFFFFFFFFu;
            vpk[2*e] = vpk[2*e + 1] = 0u;
        }
    }
    __syncthreads();
    // phase 2: reserve global run early (latency hidden under scan + phase 3),
    // then block exclusive scan of 1024 counts.
    int q = threadIdx.x, lane = q & 63, wave = q >> 6;
    uint32_t cq = h[q];
    uint32_t cq4 = (cq + 3u) & ~3u;
    uint32_t gpos = atomicAdd(&gcur[q * CSTR], cq4);
    uint32_t inc = cq;
    #pragma unroll
    for (int off = 1; off < 64; off <<= 1) {
        uint32_t n = __shfl_up(inc, off, 64);
        if (lane >= off) inc += n;
    }
    if (lane == 63) wtot[wave] = inc;
    __syncthreads();
    if (q < 16) {
        uint32_t w = wtot[q];
        #pragma unroll
        for (int off = 1; off < 16; off <<= 1) {
            uint32_t n = __shfl_up(w, off, 16);
            if (q >= off) w += n;
        }
        wtot[q] = w;
    }
    __syncthreads();
    uint32_t lstart = (wave ? wtot[wave - 1] : 0u) + inc - cq;
    h[q] = lstart;                                      // placement cursor
    __syncthreads();
    // phase 3: place into LDS bucket-sorted order
    #pragma unroll
    for (int e = 0; e < 8; ++e) {
        if (a[e] != 0xFFFFFFFFu) {
            uint32_t qq = a[e] >> 14;
            uint32_t u = (vpk[e >> 1] >> ((e & 1) * 16)) & 0xFFFFu;
            srt[atomicAdd(&h[qq], 1u)] = (u << 16) | (a[e] & 16383u);
        }
    }
    __syncthreads();
    // phase 4: thread q writes bucket q's run to its reserved global slot.
    // 16B-aligned (RSLOT, gpos, cq4 all multiples of 4), zero-padded tail.
    {
        uint32_t wbase = (uint32_t)q * RSLOT + gpos;
        for (uint32_t n = 0; n < cq4; n += 4) {
            uint4 w;
            w.x = (n + 0 < cq) ? srt[lstart + n + 0] : 0u;
            w.y = (n + 1 < cq) ? srt[lstart + n + 1] : 0u;
            w.z = (n + 2 < cq) ? srt[lstart + n + 2] : 0u;
            w.w = (n + 3 < cq) ? srt[lstart + n + 3] : 0u;
            *(uint4*)(rec + wbase + n) = w;
        }
    }
}

// K2: per-bucket LDS accumulate from a CONTIGUOUS record run (fully coalesced
// dwordx4 — replaces R3's 489-deep dependent {LDS->scattered-32B->atomic}
// chain). Batch-per-XCD swizzle keeps each XCD in its batch's 2.75 MB region.
__global__ void __launch_bounds__(1024, 8) accum_k(const uint32_t* __restrict__ rec,
                                                   const uint32_t* __restrict__ gcur,
                                                   uint16_t* __restrict__ faces,
                                                   float2* __restrict__ pa) {
    __shared__ float g[16384];   // voxel (s = il*32+jl, kl) at gaddr(s,kl)
    int qb = ((blockIdx.x & 7) << 7) | (blockIdx.x >> 3);   // bijective, batch-per-XCD
    {
        float4 z = make_float4(0.f, 0.f, 0.f, 0.f);
        #pragma unroll
        for (int c = 0; c < 4; ++c)
            *(float4*)&g[(threadIdx.x + c * 1024) * 4] = z;
    }
    __syncthreads();
    {
        uint32_t count4 = gcur[qb * CSTR];           // total reserved (mult of 4)
        const uint32_t* rp = rec + (size_t)qb * RSLOT;
        for (uint32_t r = threadIdx.x * 4; r < count4; r += 4096) {
            uint4 e4 = *(const uint4*)(rp + r);
            uint32_t es[4] = {e4.x, e4.y, e4.z, e4.w};
            #pragma unroll
            for (int u = 0; u < 4; ++u) {
                uint32_t e = es[u];
                int l = e & 16383;
                atomicAdd(&g[gaddr(l >> 4, l & 15)], __uint_as_float(e & 0xFFFF0000u));
            }
        }
    }
    __syncthreads();
    // stencil: thread t owns line s = t (il = t>>5, jl = t&31)
    float tv = 0.f, mse = 0.f;
    {
        int s = threadIdx.x;
        int jl = s & 31, il = s >> 5;
        bool jin = jl < 31, iin = il < 31;
        float own[16];
        #pragma unroll
        for (int c = 0; c < 4; ++c)
            *(float4*)&own[c * 4] = *(const float4*)&g[s * 16 + goff(s, c)];
        #pragma unroll
        for (int k = 0; k < 15; ++k) {
            float d = own[k + 1] - own[k]; tv += fabsf(d); mse += d * d;
        }
        #pragma unroll
        for (int hh = 0; hh < 2; ++hh) {
            if (jin) {
                float jn[8];
                *(float4*)&jn[0] = *(const float4*)&g[(s + 1) * 16 + goff(s + 1, 2 * hh)];
                *(float4*)&jn[4] = *(const float4*)&g[(s + 1) * 16 + goff(s + 1, 2 * hh + 1)];
                #pragma unroll
                for (int k = 0; k < 8; ++k) {
                    float d = jn[k] - own[8 * hh + k]; tv += fabsf(d); mse += d * d;
                }
            }
            if (iin) {
                float inb[8];
                *(float4*)&inb[0] = *(const float4*)&g[(s + 32) * 16 + goff(s + 32, 2 * hh)];
                *(float4*)&inb[4] = *(const float4*)&g[(s + 32) * 16 + goff(s + 32, 2 * hh + 1)];
                #pragma unroll
                for (int k = 0; k < 8; ++k) {
                    float d = inb[k] - own[8 * hh + k]; tv += fabsf(d); mse += d * d;
                }
            }
        }
    }
    // faces (ushort = top-16 float bits): layout as before
    {
        uint16_t* f = faces + (size_t)qb * 4096;
        int t = threadIdx.x;
        if (t < 512) {
            int hi = t >> 4, lo = t & 15;
            f[t]        = (uint16_t)(__float_as_uint(g[gaddr(hi, lo)]) >> 16);
            f[512 + t]  = (uint16_t)(__float_as_uint(g[gaddr(992 + hi, lo)]) >> 16);
            f[1024 + t] = (uint16_t)(__float_as_uint(g[gaddr(hi * 32, lo)]) >> 16);
            f[1536 + t] = (uint16_t)(__float_as_uint(g[gaddr(hi * 32 + 31, lo)]) >> 16);
        }
        f[2048 + t] = (uint16_t)(__float_as_uint(g[gaddr(t, 0)]) >> 16);
        f[3072 + t] = (uint16_t)(__float_as_uint(g[gaddr(t, 15)]) >> 16);
    }
    block_reduce2<1024>(tv, mse);
    if (threadIdx.x == 0) pa[qb] = make_float2(tv, mse);
}

// K3: cross-sub-block interface diffs from face arrays (batch-major partials)
__global__ void __launch_bounds__(256) boundary_k(const uint16_t* __restrict__ faces,
                                                  float2* __restrict__ pb) {
    int x = blockIdx.x;
    int b = x / NIFACE;
    int r = x - b * NIFACE;
    int qA, qB, fA, fB, elems;
    if (r < 96) {                       // axis i
        int s = r >> 5, u = (r >> 3) & 3, w = r & 7;
        qA = (b << 7) | (s << 5) | (u << 3) | w; qB = qA + 32;
        fA = 512; fB = 0; elems = 512;
    } else if (r < 192) {               // axis j
        int r2 = r - 96;
        int s = r2 >> 5, u = (r2 >> 3) & 3, w = r2 & 7;
        qA = (b << 7) | (u << 5) | (s << 3) | w; qB = qA + 8;
        fA = 1536; fB = 1024; elems = 512;
    } else {                            // axis k
        int r2 = r - 192;
        int s = r2 >> 4, u = (r2 >> 2) & 3, v = r2 & 3;
        qA = (b << 7) | (u << 5) | (v << 3) | s; qB = qA + 1;
        fA = 3072; fB = 2048; elems = 1024;
    }
    const uint16_t* pA = faces + (size_t)qA * 4096 + fA;
    const uint16_t* pB = faces + (size_t)qB * 4096 + fB;
    float tv = 0.f, mse = 0.f;
    for (int e = threadIdx.x; e < elems; e += 256) {
        float d = f16up(pB[e]) - f16up(pA[e]);
        tv += fabsf(d); mse += d * d;
    }
    block_reduce2<256>(tv, mse);
    if (threadIdx.x == 0) pb[x] = make_float2(tv, mse);
}

// K4: final reduction — one block per batch, no atomics
__global__ void __launch_bounds__(256) final_k(const float2* __restrict__ pa,
                                               const float2* __restrict__ pb,
                                               float* __restrict__ out) {
    int b = blockIdx.x;
    float tv = 0.f, mse = 0.f;
    const float2* a = pa + (size_t)b * (NBQ / BATCH);
    for (int i = threadIdx.x; i < NBQ / BATCH; i += 256) { float2 v = a[i]; tv += v.x; mse += v.y; }
    const float2* p = pb + (size_t)b * NIFACE;
    for (int i = threadIdx.x; i < NIFACE; i += 256) { float2 v = p[i]; tv += v.x; mse += v.y; }
    block_reduce2<256>(tv, mse);
    if (threadIdx.x == 0) {
        out[b]     = tv  * (1.f / 2097152.f);   // / X^3
        out[8 + b] = mse * (1.f / 32512.f);     // / (2X^2-2X)
    }
}

extern "C" void kernel_launch(void* const* d_in, const int* in_sizes, int n_in,
                              void* d_out, int out_size, void* d_ws, size_t ws_size,
                              hipStream_t stream) {
    const int*   indices = (const int*)d_in[0];   // (B, M, 3) int32
    const float* values  = (const float*)d_in[1]; // (B, M) float32
    float*       out     = (float*)d_out;         // (2, B) float32

    // workspace (~31 MiB), 256B-aligned sections
    char* wp = (char*)d_ws;
    uint32_t* gcur  = (uint32_t*)wp;                           // 1024 cursors, 64B-strided (64 KB)
    wp += ((size_t)NBQ * CSTR * 4 + 255) & ~(size_t)255;
    float2*   pa    = (float2*)wp;                             // NBQ        (8 KB)
    wp += (NBQ * 8 + 255) & ~(size_t)255;
    float2*   pb    = (float2*)wp;                             // NBND       (19 KB)
    wp += ((size_t)NBND * 8 + 255) & ~(size_t)255;
    uint32_t* rec   = (uint32_t*)wp;                           // NBQ*RSLOT  (22 MB)
    wp += (((size_t)NBQ * RSLOT * 4) + 255) & ~(size_t)255;
    uint16_t* faces = (uint16_t*)wp;                           // NBQ*4096   (8 MB)

    hipMemsetAsync(gcur, 0, (size_t)NBQ * CSTR * 4, stream);
    sort_k    <<<NTILE, 1024, 0, stream>>>(indices, values, gcur, rec);
    accum_k   <<<NBQ,   1024, 0, stream>>>(rec, gcur, faces, pa);
    boundary_k<<<NBND,  256,  0, stream>>>(faces, pb);
    final_k   <<<BATCH, 256,  0, stream>>>(pa, pb, out);
}

// Round 9
// 152.869 us; speedup vs baseline: 2.0772x; 1.0079x over previous
//
#include <hip/hip_runtime.h>
#include <stdint.h>

#define BATCH 8
#define MPTS 500000
#define NPTS (BATCH * MPTS)            // 4,000,000
#define NBQ 1024                       // 8 batches * (4*4*8) sub-blocks of 32x32x16
#define TP 8192                        // points per tile (srt = 32 KB)
#define NTILE ((NPTS + TP - 1) / TP)   // 489
#define RSLOT 5376                     // rec slots per bucket (mean use ~4640, +11 sd)
#define CSTR 16                        // gcur stride in dwords (64 B -> own cache line)
#define NIFACE 304                     // interfaces per batch: 96 + 96 + 112
#define NBND (BATCH * NIFACE)          // 2432 boundary blocks

template <int NT>
__device__ __forceinline__ void block_reduce2(float& tv, float& mse) {
    for (int off = 32; off > 0; off >>= 1) {
        tv  += __shfl_down(tv, off, 64);
        mse += __shfl_down(mse, off, 64);
    }
    __shared__ float stv[NT / 64], sms[NT / 64];
    int w = threadIdx.x >> 6, lane = threadIdx.x & 63;
    if (lane == 0) { stv[w] = tv; sms[w] = mse; }
    __syncthreads();
    if (threadIdx.x == 0) {
        float a = 0.f, m = 0.f;
        #pragma unroll
        for (int e = 0; e < NT / 64; ++e) { a += stv[e]; m += sms[e]; }
        tv = a; mse = m;
    }
}

// aux = (q:10 | l:14); sub-block 32x32x16. aux < 2^24 -> 0xFFFFFFFF safe sentinel.
__device__ __forceinline__ uint32_t pack_aux(int b, int i, int j, int k) {
    uint32_t q = ((uint32_t)b << 7) | ((uint32_t)(i >> 5) << 5) |
                 ((uint32_t)(j >> 5) << 3) | (uint32_t)(k >> 4);
    uint32_t l = ((uint32_t)(i & 31) << 9) | ((uint32_t)(j & 31) << 4) | (uint32_t)(k & 15);
    return (q << 14) | l;
}

// LDS bank swizzle: line s = il*32+jl holds 16 dwords; group-of-4 index XORed
// with (s>>1) so wave-wide b128 reads spread across all 32 banks.
__device__ __forceinline__ int gaddr(int s, int kl) {
    return s * 16 + (kl & 3) + ((((kl >> 2) ^ (s >> 1)) & 3) << 2);
}
__device__ __forceinline__ int goff(int s, int c) {
    return ((c ^ (s >> 1)) & 3) << 2;
}

// round float bits to top-16 (sign+exp+7man), round-half-up
__device__ __forceinline__ uint32_t val16(float f) {
    return (__float_as_uint(f) + 0x8000u) >> 16;
}
__device__ __forceinline__ float f16up(uint16_t u) {
    return __uint_as_float(((uint32_t)u) << 16);
}

// K1: per-tile hist + local scan + LDS counting sort, then BUCKET-CONTIGUOUS
// global writeout. Thread q = bucket q: reserves cq4 = ceil4(cq) slots in
// bucket q's region via one returnful global atomic (64B-strided cursors),
// then writes its run as aligned dwordx4. Tail pads are value +0.0f with a
// SPREAD voxel address ((gpos+n)&16383) — R8 lesson: pad record 0u sent ~730
// same-address LDS atomics per accum block to gaddr(0,0), which serialize
// (~12 us/block). +0.0f at any voxel is numerically inert.
__global__ void __launch_bounds__(1024, 8) sort_k(const int* __restrict__ idx,
                                                  const float* __restrict__ val,
                                                  uint32_t* __restrict__ gcur,
                                                  uint32_t* __restrict__ rec) {
    __shared__ uint32_t h[NBQ];     // counts -> placement cursors
    __shared__ uint32_t wtot[16];
    __shared__ uint32_t srt[TP];    // bucket-sorted packed records (32 KB)
    int tile = blockIdx.x;
    int p0 = tile * TP;
    int cnt = min(TP, NPTS - p0);   // always a multiple of 4
    h[threadIdx.x] = 0;
    __syncthreads();
    // phase 1: vectorized loads (4 points = 3 int4 + 1 float4), LDS histogram.
    uint32_t a[8]; uint32_t vpk[4];
    int ng = cnt >> 2;
    #pragma unroll
    for (int e = 0; e < 2; ++e) {
        int g = threadIdx.x + e * 1024;
        if (g < ng) {
            int p = p0 + g * 4;
            const int4* ip = (const int4*)(idx + (size_t)p * 3);
            int4 A = ip[0], B = ip[1], C = ip[2];
            float4 V = *(const float4*)(val + p);
            int b = p / MPTS;       // groups of 4 never straddle a batch
            a[4*e+0] = pack_aux(b, A.x, A.y, A.z);
            a[4*e+1] = pack_aux(b, A.w, B.x, B.y);
            a[4*e+2] = pack_aux(b, B.z, B.w, C.x);
            a[4*e+3] = pack_aux(b, C.y, C.z, C.w);
            vpk[2*e]     = val16(V.x) | (val16(V.y) << 16);
            vpk[2*e + 1] = val16(V.z) | (val16(V.w) << 16);
            #pragma unroll
            for (int u = 0; u < 4; ++u) atomicAdd(&h[a[4*e+u] >> 14], 1u);
        } else {
            a[4*e+0] = a[4*e+1] = a[4*e+2] = a[4*e+3] = 0xFFFFFFFFu;
            vpk[2*e] = vpk[2*e + 1] = 0u;
        }
    }
    __syncthreads();
    // phase 2: reserve global run early (latency hidden under scan + phase 3),
    // then block exclusive scan of 1024 counts.
    int q = threadIdx.x, lane = q & 63, wave = q >> 6;
    uint32_t cq = h[q];
    uint32_t cq4 = (cq + 3u) & ~3u;
    uint32_t gpos = atomicAdd(&gcur[q * CSTR], cq4);
    uint32_t inc = cq;
    #pragma unroll
    for (int off = 1; off < 64; off <<= 1) {
        uint32_t n = __shfl_up(inc, off, 64);
        if (lane >= off) inc += n;
    }
    if (lane == 63) wtot[wave] = inc;
    __syncthreads();
    if (q < 16) {
        uint32_t w = wtot[q];
        #pragma unroll
        for (int off = 1; off < 16; off <<= 1) {
            uint32_t n = __shfl_up(w, off, 16);
            if (q >= off) w += n;
        }
        wtot[q] = w;
    }
    __syncthreads();
    uint32_t lstart = (wave ? wtot[wave - 1] : 0u) + inc - cq;
    h[q] = lstart;                                      // placement cursor
    __syncthreads();
    // phase 3: place into LDS bucket-sorted order
    #pragma unroll
    for (int e = 0; e < 8; ++e) {
        if (a[e] != 0xFFFFFFFFu) {
            uint32_t qq = a[e] >> 14;
            uint32_t u = (vpk[e >> 1] >> ((e & 1) * 16)) & 0xFFFFu;
            srt[atomicAdd(&h[qq], 1u)] = (u << 16) | (a[e] & 16383u);
        }
    }
    __syncthreads();
    // phase 4: thread q writes bucket q's run to its reserved global slot.
    // 16B-aligned (RSLOT, gpos, cq4 all multiples of 4); inert spread pads.
    {
        uint32_t wbase = (uint32_t)q * RSLOT + gpos;
        for (uint32_t n = 0; n < cq4; n += 4) {
            uint4 w;
            w.x = (n + 0 < cq) ? srt[lstart + n + 0] : ((gpos + n + 0) & 16383u);
            w.y = (n + 1 < cq) ? srt[lstart + n + 1] : ((gpos + n + 1) & 16383u);
            w.z = (n + 2 < cq) ? srt[lstart + n + 2] : ((gpos + n + 2) & 16383u);
            w.w = (n + 3 < cq) ? srt[lstart + n + 3] : ((gpos + n + 3) & 16383u);
            *(uint4*)(rec + wbase + n) = w;
        }
    }
}

// K2: per-bucket LDS accumulate from a CONTIGUOUS record run (fully coalesced
// dwordx4). Batch-per-XCD swizzle keeps each XCD in its batch's region.
__global__ void __launch_bounds__(1024, 8) accum_k(const uint32_t* __restrict__ rec,
                                                   const uint32_t* __restrict__ gcur,
                                                   uint16_t* __restrict__ faces,
                                                   float2* __restrict__ pa) {
    __shared__ float g[16384];   // voxel (s = il*32+jl, kl) at gaddr(s,kl)
    int qb = ((blockIdx.x & 7) << 7) | (blockIdx.x >> 3);   // bijective, batch-per-XCD
    {
        float4 z = make_float4(0.f, 0.f, 0.f, 0.f);
        #pragma unroll
        for (int c = 0; c < 4; ++c)
            *(float4*)&g[(threadIdx.x + c * 1024) * 4] = z;
    }
    __syncthreads();
    {
        uint32_t count4 = gcur[qb * CSTR];           // total reserved (mult of 4)
        const uint32_t* rp = rec + (size_t)qb * RSLOT;
        for (uint32_t r = threadIdx.x * 4; r < count4; r += 4096) {
            uint4 e4 = *(const uint4*)(rp + r);
            uint32_t es[4] = {e4.x, e4.y, e4.z, e4.w};
            #pragma unroll
            for (int u = 0; u < 4; ++u) {
                uint32_t e = es[u];
                int l = e & 16383;
                atomicAdd(&g[gaddr(l >> 4, l & 15)], __uint_as_float(e & 0xFFFF0000u));
            }
        }
    }
    __syncthreads();
    // stencil: thread t owns line s = t (il = t>>5, jl = t&31)
    float tv = 0.f, mse = 0.f;
    {
        int s = threadIdx.x;
        int jl = s & 31, il = s >> 5;
        bool jin = jl < 31, iin = il < 31;
        float own[16];
        #pragma unroll
        for (int c = 0; c < 4; ++c)
            *(float4*)&own[c * 4] = *(const float4*)&g[s * 16 + goff(s, c)];
        #pragma unroll
        for (int k = 0; k < 15; ++k) {
            float d = own[k + 1] - own[k]; tv += fabsf(d); mse += d * d;
        }
        #pragma unroll
        for (int hh = 0; hh < 2; ++hh) {
            if (jin) {
                float jn[8];
                *(float4*)&jn[0] = *(const float4*)&g[(s + 1) * 16 + goff(s + 1, 2 * hh)];
                *(float4*)&jn[4] = *(const float4*)&g[(s + 1) * 16 + goff(s + 1, 2 * hh + 1)];
                #pragma unroll
                for (int k = 0; k < 8; ++k) {
                    float d = jn[k] - own[8 * hh + k]; tv += fabsf(d); mse += d * d;
                }
            }
            if (iin) {
                float inb[8];
                *(float4*)&inb[0] = *(const float4*)&g[(s + 32) * 16 + goff(s + 32, 2 * hh)];
                *(float4*)&inb[4] = *(const float4*)&g[(s + 32) * 16 + goff(s + 32, 2 * hh + 1)];
                #pragma unroll
                for (int k = 0; k < 8; ++k) {
                    float d = inb[k] - own[8 * hh + k]; tv += fabsf(d); mse += d * d;
                }
            }
        }
    }
    // faces (ushort = top-16 float bits): layout as before
    {
        uint16_t* f = faces + (size_t)qb * 4096;
        int t = threadIdx.x;
        if (t < 512) {
            int hi = t >> 4, lo = t & 15;
            f[t]        = (uint16_t)(__float_as_uint(g[gaddr(hi, lo)]) >> 16);
            f[512 + t]  = (uint16_t)(__float_as_uint(g[gaddr(992 + hi, lo)]) >> 16);
            f[1024 + t] = (uint16_t)(__float_as_uint(g[gaddr(hi * 32, lo)]) >> 16);
            f[1536 + t] = (uint16_t)(__float_as_uint(g[gaddr(hi * 32 + 31, lo)]) >> 16);
        }
        f[2048 + t] = (uint16_t)(__float_as_uint(g[gaddr(t, 0)]) >> 16);
        f[3072 + t] = (uint16_t)(__float_as_uint(g[gaddr(t, 15)]) >> 16);
    }
    block_reduce2<1024>(tv, mse);
    if (threadIdx.x == 0) pa[qb] = make_float2(tv, mse);
}

// K3: cross-sub-block interface diffs from face arrays (batch-major partials)
__global__ void __launch_bounds__(256) boundary_k(const uint16_t* __restrict__ faces,
                                                  float2* __restrict__ pb) {
    int x = blockIdx.x;
    int b = x / NIFACE;
    int r = x - b * NIFACE;
    int qA, qB, fA, fB, elems;
    if (r < 96) {                       // axis i
        int s = r >> 5, u = (r >> 3) & 3, w = r & 7;
        qA = (b << 7) | (s << 5) | (u << 3) | w; qB = qA + 32;
        fA = 512; fB = 0; elems = 512;
    } else if (r < 192) {               // axis j
        int r2 = r - 96;
        int s = r2 >> 5, u = (r2 >> 3) & 3, w = r2 & 7;
        qA = (b << 7) | (u << 5) | (s << 3) | w; qB = qA + 8;
        fA = 1536; fB = 1024; elems = 512;
    } else {                            // axis k
        int r2 = r - 192;
        int s = r2 >> 4, u = (r2 >> 2) & 3, v = r2 & 3;
        qA = (b << 7) | (u << 5) | (v << 3) | s; qB = qA + 1;
        fA = 3072; fB = 2048; elems = 1024;
    }
    const uint16_t* pA = faces + (size_t)qA * 4096 + fA;
    const uint16_t* pB = faces + (size_t)qB * 4096 + fB;
    float tv = 0.f, mse = 0.f;
    for (int e = threadIdx.x; e < elems; e += 256) {
        float d = f16up(pB[e]) - f16up(pA[e]);
        tv += fabsf(d); mse += d * d;
    }
    block_reduce2<256>(tv, mse);
    if (threadIdx.x == 0) pb[x] = make_float2(tv, mse);
}

// K4: final reduction — one block per batch, no atomics
__global__ void __launch_bounds__(256) final_k(const float2* __restrict__ pa,
                                               const float2* __restrict__ pb,
                                               float* __restrict__ out) {
    int b = blockIdx.x;
    float tv = 0.f, mse = 0.f;
    const float2* a = pa + (size_t)b * (NBQ / BATCH);
    for (int i = threadIdx.x; i < NBQ / BATCH; i += 256) { float2 v = a[i]; tv += v.x; mse += v.y; }
    const float2* p = pb + (size_t)b * NIFACE;
    for (int i = threadIdx.x; i < NIFACE; i += 256) { float2 v = p[i]; tv += v.x; mse += v.y; }
    block_reduce2<256>(tv, mse);
    if (threadIdx.x == 0) {
        out[b]     = tv  * (1.f / 2097152.f);   // / X^3
        out[8 + b] = mse * (1.f / 32512.f);     // / (2X^2-2X)
    }
}

extern "C" void kernel_launch(void* const* d_in, const int* in_sizes, int n_in,
                              void* d_out, int out_size, void* d_ws, size_t ws_size,
                              hipStream_t stream) {
    const int*   indices = (const int*)d_in[0];   // (B, M, 3) int32
    const float* values  = (const float*)d_in[1]; // (B, M) float32
    float*       out     = (float*)d_out;         // (2, B) float32

    // workspace (~31 MiB), 256B-aligned sections
    char* wp = (char*)d_ws;
    uint32_t* gcur  = (uint32_t*)wp;                           // 1024 cursors, 64B-strided (64 KB)
    wp += ((size_t)NBQ * CSTR * 4 + 255) & ~(size_t)255;
    float2*   pa    = (float2*)wp;                             // NBQ        (8 KB)
    wp += (NBQ * 8 + 255) & ~(size_t)255;
    float2*   pb    = (float2*)wp;                             // NBND       (19 KB)
    wp += ((size_t)NBND * 8 + 255) & ~(size_t)255;
    uint32_t* rec   = (uint32_t*)wp;                           // NBQ*RSLOT  (22 MB)
    wp += (((size_t)NBQ * RSLOT * 4) + 255) & ~(size_t)255;
    uint16_t* faces = (uint16_t*)wp;                           // NBQ*4096   (8 MB)

    hipMemsetAsync(gcur, 0, (size_t)NBQ * CSTR * 4, stream);
    sort_k    <<<NTILE, 1024, 0, stream>>>(indices, values, gcur, rec);
    accum_k   <<<NBQ,   1024, 0, stream>>>(rec, gcur, faces, pa);
    boundary_k<<<NBND,  256,  0, stream>>>(faces, pb);
    final_k   <<<BATCH, 256,  0, stream>>>(pa, pb, out);
}

// Round 10
// 137.461 us; speedup vs baseline: 2.3100x; 1.1121x over previous
//
#include <hip/hip_runtime.h>
#include <stdint.h>

#define BATCH 8
#define MPTS 500000
#define NPTS (BATCH * MPTS)            // 4,000,000
#define NBQ 1024                       // 8 batches * (4*4*8) sub-blocks of 32x32x16
#define TP 8192                        // points per tile (srt = 32 KB)
#define NTILE ((NPTS + TP - 1) / TP)   // 489
#define HROW (NBQ + 1)                 // offsets row stride (last entry = tile cnt)
#define NIFACE 304                     // interfaces per batch: 96 + 96 + 112
#define NBND (BATCH * NIFACE)          // 2432 boundary blocks

template <int NT>
__device__ __forceinline__ void block_reduce2(float& tv, float& mse) {
    for (int off = 32; off > 0; off >>= 1) {
        tv  += __shfl_down(tv, off, 64);
        mse += __shfl_down(mse, off, 64);
    }
    __shared__ float stv[NT / 64], sms[NT / 64];
    int w = threadIdx.x >> 6, lane = threadIdx.x & 63;
    if (lane == 0) { stv[w] = tv; sms[w] = mse; }
    __syncthreads();
    if (threadIdx.x == 0) {
        float a = 0.f, m = 0.f;
        #pragma unroll
        for (int e = 0; e < NT / 64; ++e) { a += stv[e]; m += sms[e]; }
        tv = a; mse = m;
    }
}

// aux = (q:10 | l:14); sub-block 32x32x16. aux < 2^24 -> 0xFFFFFFFF safe sentinel.
__device__ __forceinline__ uint32_t pack_aux(int b, int i, int j, int k) {
    uint32_t q = ((uint32_t)b << 7) | ((uint32_t)(i >> 5) << 5) |
                 ((uint32_t)(j >> 5) << 3) | (uint32_t)(k >> 4);
    uint32_t l = ((uint32_t)(i & 31) << 9) | ((uint32_t)(j & 31) << 4) | (uint32_t)(k & 15);
    return (q << 14) | l;
}

// LDS bank swizzle: line s = il*32+jl holds 16 dwords; group-of-4 index XORed
// with (s>>1) so wave-wide b128 reads spread across all 32 banks.
__device__ __forceinline__ int gaddr(int s, int kl) {
    return s * 16 + (kl & 3) + ((((kl >> 2) ^ (s >> 1)) & 3) << 2);
}
__device__ __forceinline__ int goff(int s, int c) {
    return ((c ^ (s >> 1)) & 3) << 2;
}

// round float bits to top-16 (sign+exp+7man), round-half-up
__device__ __forceinline__ uint32_t val16(float f) {
    return (__float_as_uint(f) + 0x8000u) >> 16;
}
__device__ __forceinline__ float f16up(uint16_t u) {
    return __uint_as_float(((uint32_t)u) << 16);
}

// K1: fused per-tile hist + local exclusive scan + LDS counting sort + coalesced
// writeout. Record = (val16 << 16) | local14 (bits 14-15 zero).
// R9 lesson: launch_bounds(1024,8) let the compiler allocate 20 VGPRs -> the
// two phase-1 load rounds serialized (1 HBM round-trip in flight). Now
// min-waves=4 (128-VGPR cap; LDS still caps at 2 blocks/CU = 32 waves, no
// occupancy loss) and ALL loads are issued before any use.
__global__ void __launch_bounds__(1024, 4) sort_k(const int* __restrict__ idx,
                                                  const float* __restrict__ val,
                                                  uint16_t* __restrict__ hoff,
                                                  uint32_t* __restrict__ rec) {
    __shared__ uint32_t h[NBQ];     // counts -> placement cursors
    __shared__ uint32_t wtot[16];
    __shared__ uint32_t srt[TP];    // sorted packed records (32 KB)
    int tile = blockIdx.x;
    int p0 = tile * TP;
    int cnt = min(TP, NPTS - p0);   // always a multiple of 4
    h[threadIdx.x] = 0;
    // phase 1: issue ALL global loads first (8x 16B in flight), then pack+hist.
    int ng = cnt >> 2;
    int g0 = threadIdx.x, g1 = threadIdx.x + 1024;
    bool v0 = g0 < ng, v1 = g1 < ng;
    int4 A0, B0, C0, A1, B1, C1;
    float4 V0, V1;
    int pp0 = p0 + g0 * 4, pp1 = p0 + g1 * 4;
    if (v0) {
        const int4* ip = (const int4*)(idx + (size_t)pp0 * 3);
        A0 = ip[0]; B0 = ip[1]; C0 = ip[2];
        V0 = *(const float4*)(val + pp0);
    }
    if (v1) {
        const int4* ip = (const int4*)(idx + (size_t)pp1 * 3);
        A1 = ip[0]; B1 = ip[1]; C1 = ip[2];
        V1 = *(const float4*)(val + pp1);
    }
    __syncthreads();                 // h[] zero-init visible
    uint32_t a[8]; uint32_t vpk[4];
    if (v0) {
        int b = pp0 / MPTS;          // groups of 4 never straddle a batch
        a[0] = pack_aux(b, A0.x, A0.y, A0.z);
        a[1] = pack_aux(b, A0.w, B0.x, B0.y);
        a[2] = pack_aux(b, B0.z, B0.w, C0.x);
        a[3] = pack_aux(b, C0.y, C0.z, C0.w);
        vpk[0] = val16(V0.x) | (val16(V0.y) << 16);
        vpk[1] = val16(V0.z) | (val16(V0.w) << 16);
        #pragma unroll
        for (int u = 0; u < 4; ++u) atomicAdd(&h[a[u] >> 14], 1u);
    } else {
        a[0] = a[1] = a[2] = a[3] = 0xFFFFFFFFu;
        vpk[0] = vpk[1] = 0u;
    }
    if (v1) {
        int b = pp1 / MPTS;
        a[4] = pack_aux(b, A1.x, A1.y, A1.z);
        a[5] = pack_aux(b, A1.w, B1.x, B1.y);
        a[6] = pack_aux(b, B1.z, B1.w, C1.x);
        a[7] = pack_aux(b, C1.y, C1.z, C1.w);
        vpk[2] = val16(V1.x) | (val16(V1.y) << 16);
        vpk[3] = val16(V1.z) | (val16(V1.w) << 16);
        #pragma unroll
        for (int u = 4; u < 8; ++u) atomicAdd(&h[a[u] >> 14], 1u);
    } else {
        a[4] = a[5] = a[6] = a[7] = 0xFFFFFFFFu;
        vpk[2] = vpk[3] = 0u;
    }
    __syncthreads();
    // phase 2: block exclusive scan of 1024 counts (wave shuffles, 2 barriers)
    int q = threadIdx.x, lane = q & 63, wave = q >> 6;
    uint32_t cq = h[q];
    uint32_t inc = cq;
    #pragma unroll
    for (int off = 1; off < 64; off <<= 1) {
        uint32_t n = __shfl_up(inc, off, 64);
        if (lane >= off) inc += n;
    }
    if (lane == 63) wtot[wave] = inc;
    __syncthreads();
    if (q < 16) {
        uint32_t w = wtot[q];
        #pragma unroll
        for (int off = 1; off < 16; off <<= 1) {
            uint32_t n = __shfl_up(w, off, 16);
            if (q >= off) w += n;
        }
        wtot[q] = w;
    }
    __syncthreads();
    uint32_t lstart = (wave ? wtot[wave - 1] : 0u) + inc - cq;
    hoff[(size_t)tile * HROW + q] = (uint16_t)lstart;   // tile-local start offset
    if (q == 0) hoff[(size_t)tile * HROW + NBQ] = (uint16_t)cnt;
    h[q] = lstart;                                      // placement cursor
    __syncthreads();
    // phase 3: place into LDS sorted order
    #pragma unroll
    for (int e = 0; e < 8; ++e) {
        if (a[e] != 0xFFFFFFFFu) {
            uint32_t qq = a[e] >> 14;
            uint32_t u = (vpk[e >> 1] >> ((e & 1) * 16)) & 0xFFFFu;
            srt[atomicAdd(&h[qq], 1u)] = (u << 16) | (a[e] & 16383u);
        }
    }
    __syncthreads();
    // phase 4: fully coalesced linear writeout (uint4)
    uint4* recq = (uint4*)(rec + (size_t)tile * TP);
    const uint4* sr4 = (const uint4*)srt;
    for (int s = threadIdx.x; s < (cnt >> 2); s += 1024) recq[s] = sr4[s];
}

// K2: per-bucket LDS accumulate. XCD-chunked qb swizzle (batch = blockIdx&7).
// Gather is a 4-way UNROLLED walk over tiles {grp, +128, +256, +384}: four
// independent record streams -> 4 global loads in flight per step instead of
// R3's single dependent {LDS offset -> 32B load -> LDS atomic} chain.
// min-waves=4 raises the VGPR cap (was 28 regs under (1024,8)).
__global__ void __launch_bounds__(1024, 4) accum_k(const uint32_t* __restrict__ rec,
                                                   const uint16_t* __restrict__ hoff,
                                                   uint16_t* __restrict__ faces,
                                                   float2* __restrict__ pa) {
    __shared__ float g[16384];   // voxel (s = il*32+jl, kl) at gaddr(s,kl)
    __shared__ uint16_t sA[NTILE], sB[NTILE];
    int qb = ((blockIdx.x & 7) << 7) | (blockIdx.x >> 3);   // bijective, batch-per-XCD
    // prefetch hoff columns qb, qb+1 (978 scattered 2B loads, one parallel burst)
    if (threadIdx.x < NTILE) {
        const uint16_t* row = hoff + (size_t)threadIdx.x * HROW + qb;
        sA[threadIdx.x] = row[0];
        sB[threadIdx.x] = row[1];
    }
    {
        float4 z = make_float4(0.f, 0.f, 0.f, 0.f);
        #pragma unroll
        for (int c = 0; c < 4; ++c)
            *(float4*)&g[(threadIdx.x + c * 1024) * 4] = z;
    }
    __syncthreads();
    {
        int grp = threadIdx.x >> 3;      // 0..127
        int r8  = threadIdx.x & 7;
        uint32_t rr[4], re[4];
        const uint32_t* rp[4];
        #pragma unroll
        for (int u = 0; u < 4; ++u) {
            int t = grp + u * 128;
            if (t < NTILE) {
                rr[u] = (uint32_t)sA[t] + r8;
                re[u] = sB[t];
                rp[u] = rec + (size_t)t * TP;
            } else {
                rr[u] = 1u; re[u] = 0u; rp[u] = rec;
            }
        }
        bool any = true;
        while (any) {
            any = false;
            uint32_t e[4]; bool act[4];
            #pragma unroll
            for (int u = 0; u < 4; ++u) {
                act[u] = rr[u] < re[u];
                if (act[u]) e[u] = rp[u][rr[u]];   // 4 independent loads in flight
            }
            #pragma unroll
            for (int u = 0; u < 4; ++u) {
                if (act[u]) {
                    int l = e[u] & 16383;
                    atomicAdd(&g[gaddr(l >> 4, l & 15)],
                              __uint_as_float(e[u] & 0xFFFF0000u));
                    rr[u] += 8;
                    any = true;
                }
            }
        }
    }
    __syncthreads();
    // stencil: thread t owns line s = t (il = t>>5, jl = t&31)
    float tv = 0.f, mse = 0.f;
    {
        int s = threadIdx.x;
        int jl = s & 31, il = s >> 5;
        bool jin = jl < 31, iin = il < 31;
        float own[16];
        #pragma unroll
        for (int c = 0; c < 4; ++c)
            *(float4*)&own[c * 4] = *(const float4*)&g[s * 16 + goff(s, c)];
        #pragma unroll
        for (int k = 0; k < 15; ++k) {
            float d = own[k + 1] - own[k]; tv += fabsf(d); mse += d * d;
        }
        #pragma unroll
        for (int hh = 0; hh < 2; ++hh) {
            if (jin) {
                float jn[8];
                *(float4*)&jn[0] = *(const float4*)&g[(s + 1) * 16 + goff(s + 1, 2 * hh)];
                *(float4*)&jn[4] = *(const float4*)&g[(s + 1) * 16 + goff(s + 1, 2 * hh + 1)];
                #pragma unroll
                for (int k = 0; k < 8; ++k) {
                    float d = jn[k] - own[8 * hh + k]; tv += fabsf(d); mse += d * d;
                }
            }
            if (iin) {
                float inb[8];
                *(float4*)&inb[0] = *(const float4*)&g[(s + 32) * 16 + goff(s + 32, 2 * hh)];
                *(float4*)&inb[4] = *(const float4*)&g[(s + 32) * 16 + goff(s + 32, 2 * hh + 1)];
                #pragma unroll
                for (int k = 0; k < 8; ++k) {
                    float d = inb[k] - own[8 * hh + k]; tv += fabsf(d); mse += d * d;
                }
            }
        }
    }
    // faces (ushort = top-16 float bits): layout as before
    {
        uint16_t* f = faces + (size_t)qb * 4096;
        int t = threadIdx.x;
        if (t < 512) {
            int hi = t >> 4, lo = t & 15;
            f[t]        = (uint16_t)(__float_as_uint(g[gaddr(hi, lo)]) >> 16);
            f[512 + t]  = (uint16_t)(__float_as_uint(g[gaddr(992 + hi, lo)]) >> 16);
            f[1024 + t] = (uint16_t)(__float_as_uint(g[gaddr(hi * 32, lo)]) >> 16);
            f[1536 + t] = (uint16_t)(__float_as_uint(g[gaddr(hi * 32 + 31, lo)]) >> 16);
        }
        f[2048 + t] = (uint16_t)(__float_as_uint(g[gaddr(t, 0)]) >> 16);
        f[3072 + t] = (uint16_t)(__float_as_uint(g[gaddr(t, 15)]) >> 16);
    }
    block_reduce2<1024>(tv, mse);
    if (threadIdx.x == 0) pa[qb] = make_float2(tv, mse);
}

// K3: cross-sub-block interface diffs from face arrays (batch-major partials)
__global__ void __launch_bounds__(256) boundary_k(const uint16_t* __restrict__ faces,
                                                  float2* __restrict__ pb) {
    int x = blockIdx.x;
    int b = x / NIFACE;
    int r = x - b * NIFACE;
    int qA, qB, fA, fB, elems;
    if (r < 96) {                       // axis i
        int s = r >> 5, u = (r >> 3) & 3, w = r & 7;
        qA = (b << 7) | (s << 5) | (u << 3) | w; qB = qA + 32;
        fA = 512; fB = 0; elems = 512;
    } else if (r < 192) {               // axis j
        int r2 = r - 96;
        int s = r2 >> 5, u = (r2 >> 3) & 3, w = r2 & 7;
        qA = (b << 7) | (u << 5) | (s << 3) | w; qB = qA + 8;
        fA = 1536; fB = 1024; elems = 512;
    } else {                            // axis k
        int r2 = r - 192;
        int s = r2 >> 4, u = (r2 >> 2) & 3, v = r2 & 3;
        qA = (b << 7) | (u << 5) | (v << 3) | s; qB = qA + 1;
        fA = 3072; fB = 2048; elems = 1024;
    }
    const uint16_t* pA = faces + (size_t)qA * 4096 + fA;
    const uint16_t* pB = faces + (size_t)qB * 4096 + fB;
    float tv = 0.f, mse = 0.f;
    for (int e = threadIdx.x; e < elems; e += 256) {
        float d = f16up(pB[e]) - f16up(pA[e]);
        tv += fabsf(d); mse += d * d;
    }
    block_reduce2<256>(tv, mse);
    if (threadIdx.x == 0) pb[x] = make_float2(tv, mse);
}

// K4: final reduction — one block per batch, no atomics
__global__ void __launch_bounds__(256) final_k(const float2* __restrict__ pa,
                                               const float2* __restrict__ pb,
                                               float* __restrict__ out) {
    int b = blockIdx.x;
    float tv = 0.f, mse = 0.f;
    const float2* a = pa + (size_t)b * (NBQ / BATCH);
    for (int i = threadIdx.x; i < NBQ / BATCH; i += 256) { float2 v = a[i]; tv += v.x; mse += v.y; }
    const float2* p = pb + (size_t)b * NIFACE;
    for (int i = threadIdx.x; i < NIFACE; i += 256) { float2 v = p[i]; tv += v.x; mse += v.y; }
    block_reduce2<256>(tv, mse);
    if (threadIdx.x == 0) {
        out[b]     = tv  * (1.f / 2097152.f);   // / X^3
        out[8 + b] = mse * (1.f / 32512.f);     // / (2X^2-2X)
    }
}

extern "C" void kernel_launch(void* const* d_in, const int* in_sizes, int n_in,
                              void* d_out, int out_size, void* d_ws, size_t ws_size,
                              hipStream_t stream) {
    const int*   indices = (const int*)d_in[0];   // (B, M, 3) int32
    const float* values  = (const float*)d_in[1]; // (B, M) float32
    float*       out     = (float*)d_out;         // (2, B) float32

    // workspace (~25 MiB), 256B-aligned sections
    char* wp = (char*)d_ws;
    uint16_t* hoff  = (uint16_t*)wp;                           // NTILE*HROW u16 (1.0 MB)
    wp += (((size_t)NTILE * HROW * 2) + 255) & ~(size_t)255;
    float2*   pa    = (float2*)wp;                             // NBQ        (8 KB)
    wp += (NBQ * 8 + 255) & ~(size_t)255;
    float2*   pb    = (float2*)wp;                             // NBND       (19 KB)
    wp += ((size_t)NBND * 8 + 255) & ~(size_t)255;
    uint32_t* rec   = (uint32_t*)wp;                           // NTILE*TP   (16 MB)
    wp += (((size_t)NTILE * TP * 4) + 255) & ~(size_t)255;
    uint16_t* faces = (uint16_t*)wp;                           // NBQ*4096   (8 MB)

    sort_k    <<<NTILE, 1024, 0, stream>>>(indices, values, hoff, rec);
    accum_k   <<<NBQ,   1024, 0, stream>>>(rec, hoff, faces, pa);
    boundary_k<<<NBND,  256,  0, stream>>>(faces, pb);
    final_k   <<<BATCH, 256,  0, stream>>>(pa, pb, out);
}